// Round 1
// baseline (188.292 us; speedup 1.0000x reference)
//
#include <hip/hip_runtime.h>

#define DD 500   // hidden width
#define BB 64    // batch
#define TT 2048  // timesteps (only last matters)
#define KP 128   // pitch/velocity feature width
#define VCHUNKS 32
#define VPSTRIDE 512
#define NSLOTS 16

// ws layout (floats):
//   addT   : [0      , 32000)   500*64
//   h1T    : [32000  , 64000)   500*64
//   vpart  : [64000  , 80384)   32*512
//   outacc : [80384  , 81408)   16*64
//   ticket : 81408              (1, used as unsigned)
//   cval   : 81409              (scalar c = W3.bi + b3)

// ---------------------------------------------------------------------------
// K_A: embed (last timestep only) -> addT[500][64]   (blocks 0..124)
//      + vpart chunks (blocks 125..156): vpart[oc][k] = sum_{o in chunk} W3[o]*Wi[o][k]
//      + block 125 additionally zeroes outacc/ticket and computes cval.
// ---------------------------------------------------------------------------
__global__ __launch_bounds__(256) void k_front(
    const float* __restrict__ pitches, const float* __restrict__ velocities,
    const float* __restrict__ durations, const float* __restrict__ steps,
    const float* __restrict__ Wp, const float* __restrict__ bp,
    const float* __restrict__ Wv, const float* __restrict__ bv,
    const float* __restrict__ Wd, const float* __restrict__ bd,
    const float* __restrict__ Wst, const float* __restrict__ bs,
    const float* __restrict__ Wi, const float* __restrict__ W3,
    const float* __restrict__ bi, const float* __restrict__ b3,
    float* __restrict__ addT, float* __restrict__ vpart,
    float* __restrict__ outacc, float* __restrict__ ticket,
    float* __restrict__ cval)
{
    const int tid = threadIdx.x;
    const int bid = blockIdx.x;

    if (bid >= 125) {
        // ---- v-chunk: 16 o-rows, 32 independent loads in flight ----
        const int oc = bid - 125;            // 0..31
        if (oc == 0) {
            // zero the 16x64 output accumulator (1024 floats, 4/thread)
            ((float4*)outacc)[tid] = make_float4(0.f, 0.f, 0.f, 0.f);
            if (tid == 0) *(unsigned int*)ticket = 0u;
            // c = W3 . bi + b3 (wave 0)
            if (tid < 64) {
                float cs = 0.f;
                for (int j = tid; j < DD; j += 64) cs += W3[j] * bi[j];
                #pragma unroll
                for (int off = 32; off > 0; off >>= 1)
                    cs += __shfl_xor(cs, off);
                if (tid == 0) cval[0] = cs + b3[0];
            }
        }
        const int obeg = oc * 16;
        const int k0 = tid;
        const int k1 = tid + 256;
        float acc0 = 0.f, acc1 = 0.f;
        #pragma unroll
        for (int i = 0; i < 16; ++i) {
            const int o = obeg + i;
            const int oc_ = o < DD ? o : DD - 1;      // clamp (last chunk)
            const float ww = o < DD ? W3[oc_] : 0.f;
            acc0 += ww * Wi[(size_t)oc_ * DD + k0];
            if (k1 < DD) acc1 += ww * Wi[(size_t)oc_ * DD + k1];
        }
        vpart[oc * VPSTRIDE + k0] = acc0;
        if (k1 < DD) vpart[oc * VPSTRIDE + k1] = acc1;
        return;
    }

    // ---- embed path (unchanged, harness-verified) ----
    __shared__ float lds[KP * BB];  // 32 KB; [k][b] at lds[k*64 + ((b+k)&63)]
    const int b = tid & 63;
    const int o = __builtin_amdgcn_readfirstlane(bid * 4 + (tid >> 6));
    const float* __restrict__ wp = Wp + o * KP;
    const float* __restrict__ wv = Wv + o * KP;

    float a0 = 0.f, a1 = 0.f, a2 = 0.f, a3 = 0.f;

    const float4* Psrc = (const float4*)(pitches + (size_t)(TT - 1) * BB * KP);
    const float4* Vsrc = (const float4*)(velocities + (size_t)(TT - 1) * BB * KP);

    // pass 1: pitches
    for (int j = tid; j < BB * KP / 4; j += 256) {
        float4 p = Psrc[j];
        int pb = j >> 5;          // batch row (32 float4 per 128-wide row)
        int k0 = (j & 31) * 4;
        lds[(k0 + 0) * BB + ((pb + k0 + 0) & 63)] = p.x;
        lds[(k0 + 1) * BB + ((pb + k0 + 1) & 63)] = p.y;
        lds[(k0 + 2) * BB + ((pb + k0 + 2) & 63)] = p.z;
        lds[(k0 + 3) * BB + ((pb + k0 + 3) & 63)] = p.w;
    }
    __syncthreads();
    for (int k = 0; k < KP; k += 4) {
        a0 += lds[(k + 0) * BB + ((b + k + 0) & 63)] * wp[k + 0];
        a1 += lds[(k + 1) * BB + ((b + k + 1) & 63)] * wp[k + 1];
        a2 += lds[(k + 2) * BB + ((b + k + 2) & 63)] * wp[k + 2];
        a3 += lds[(k + 3) * BB + ((b + k + 3) & 63)] * wp[k + 3];
    }
    __syncthreads();

    // pass 2: velocities
    for (int j = tid; j < BB * KP / 4; j += 256) {
        float4 p = Vsrc[j];
        int pb = j >> 5;
        int k0 = (j & 31) * 4;
        lds[(k0 + 0) * BB + ((pb + k0 + 0) & 63)] = p.x;
        lds[(k0 + 1) * BB + ((pb + k0 + 1) & 63)] = p.y;
        lds[(k0 + 2) * BB + ((pb + k0 + 2) & 63)] = p.z;
        lds[(k0 + 3) * BB + ((pb + k0 + 3) & 63)] = p.w;
    }
    __syncthreads();
    for (int k = 0; k < KP; k += 4) {
        a0 += lds[(k + 0) * BB + ((b + k + 0) & 63)] * wv[k + 0];
        a1 += lds[(k + 1) * BB + ((b + k + 1) & 63)] * wv[k + 1];
        a2 += lds[(k + 2) * BB + ((b + k + 2) & 63)] * wv[k + 2];
        a3 += lds[(k + 3) * BB + ((b + k + 3) & 63)] * wv[k + 3];
    }

    const float dur = durations[(size_t)(TT - 1) * BB + b];
    const float st  = steps[(size_t)(TT - 1) * BB + b];
    addT[o * BB + b] = bp[o] + bv[o] + bd[o] + bs[o]
                     + dur * Wd[o] + st * Wst[o]
                     + (a0 + a1) + (a2 + a3);
}

// ---------------------------------------------------------------------------
// K_B: dense-1. One o-row per block; 4 waves k-split (125 k's each) + LDS
// reduce. lanes = b (coalesced 256B activation reads), weights wave-uniform.
// ---------------------------------------------------------------------------
__global__ __launch_bounds__(256) void k_dense1(
    const float* __restrict__ Ain, const float* __restrict__ W,
    const float* __restrict__ bias, float* __restrict__ Aout)
{
    __shared__ float partial[4][BB];
    const int tid = threadIdx.x;
    const int b = tid & 63;
    const int w = tid >> 6;
    const int o = blockIdx.x;                 // 0..499
    const float* __restrict__ wrow = W + o * DD;
    const int kbeg = w * 125;

    float a0 = 0.f, a1 = 0.f, a2 = 0.f, a3 = 0.f;
    float a4 = 0.f, a5 = 0.f, a6 = 0.f, a7 = 0.f;
    #pragma unroll 3
    for (int k = kbeg; k < kbeg + 120; k += 8) {   // 15 iters
        a0 += Ain[(k + 0) * BB + b] * wrow[k + 0];
        a1 += Ain[(k + 1) * BB + b] * wrow[k + 1];
        a2 += Ain[(k + 2) * BB + b] * wrow[k + 2];
        a3 += Ain[(k + 3) * BB + b] * wrow[k + 3];
        a4 += Ain[(k + 4) * BB + b] * wrow[k + 4];
        a5 += Ain[(k + 5) * BB + b] * wrow[k + 5];
        a6 += Ain[(k + 6) * BB + b] * wrow[k + 6];
        a7 += Ain[(k + 7) * BB + b] * wrow[k + 7];
    }
    {
        const int k = kbeg + 120;                  // 5-element tail
        a0 += Ain[(k + 0) * BB + b] * wrow[k + 0];
        a1 += Ain[(k + 1) * BB + b] * wrow[k + 1];
        a2 += Ain[(k + 2) * BB + b] * wrow[k + 2];
        a3 += Ain[(k + 3) * BB + b] * wrow[k + 3];
        a4 += Ain[(k + 4) * BB + b] * wrow[k + 4];
    }
    partial[w][b] = ((a0 + a1) + (a2 + a3)) + ((a4 + a5) + (a6 + a7));
    __syncthreads();
    if (w == 0) {
        float acc = bias[o] + (partial[0][b] + partial[1][b])
                            + (partial[2][b] + partial[3][b]);
        acc = acc > 0.f ? acc : 0.01f * acc;
        Aout[o * BB + b] = acc;
    }
}

// ---------------------------------------------------------------------------
// K_C: dense-2 fused with the output contraction.
//   wave 1 pre-loads the 32 vpart entries for this o and reduces them to
//   vv[o] (latency hidden under the main loop). After the LDS reduce, wave 0
//   computes h2[o][b], adds vv[o]*h2 into a 16-slot staggered accumulator via
//   device-scope atomics, and the last-finishing block (ticket) does the
//   16-slot sum + c + sigmoid -> out[b]. No h2T round trip, no k_out launch.
// ---------------------------------------------------------------------------
__global__ __launch_bounds__(256) void k_dense2_out(
    const float* __restrict__ Ain, const float* __restrict__ W,
    const float* __restrict__ bias, const float* __restrict__ vpart,
    const float* __restrict__ cval, float* __restrict__ outacc,
    float* __restrict__ ticket, float* __restrict__ out)
{
    __shared__ float partial[4][BB];
    __shared__ float vvs;
    const int tid = threadIdx.x;
    const int b = tid & 63;
    const int w = tid >> 6;
    const int o = blockIdx.x;                 // 0..499
    const float* __restrict__ wrow = W + o * DD;
    const int kbeg = w * 125;

    // wave 1: issue the 32 vpart loads for this row up front (hidden latency)
    float vvl = 0.f;
    if (w == 1 && b < 32) vvl = vpart[b * VPSTRIDE + o];

    float a0 = 0.f, a1 = 0.f, a2 = 0.f, a3 = 0.f;
    float a4 = 0.f, a5 = 0.f, a6 = 0.f, a7 = 0.f;
    #pragma unroll 3
    for (int k = kbeg; k < kbeg + 120; k += 8) {   // 15 iters
        a0 += Ain[(k + 0) * BB + b] * wrow[k + 0];
        a1 += Ain[(k + 1) * BB + b] * wrow[k + 1];
        a2 += Ain[(k + 2) * BB + b] * wrow[k + 2];
        a3 += Ain[(k + 3) * BB + b] * wrow[k + 3];
        a4 += Ain[(k + 4) * BB + b] * wrow[k + 4];
        a5 += Ain[(k + 5) * BB + b] * wrow[k + 5];
        a6 += Ain[(k + 6) * BB + b] * wrow[k + 6];
        a7 += Ain[(k + 7) * BB + b] * wrow[k + 7];
    }
    {
        const int k = kbeg + 120;                  // 5-element tail
        a0 += Ain[(k + 0) * BB + b] * wrow[k + 0];
        a1 += Ain[(k + 1) * BB + b] * wrow[k + 1];
        a2 += Ain[(k + 2) * BB + b] * wrow[k + 2];
        a3 += Ain[(k + 3) * BB + b] * wrow[k + 3];
        a4 += Ain[(k + 4) * BB + b] * wrow[k + 4];
    }
    partial[w][b] = ((a0 + a1) + (a2 + a3)) + ((a4 + a5) + (a6 + a7));

    if (w == 1) {
        // lanes 32..63 contribute 0; xor offsets <32 keep halves separate
        #pragma unroll
        for (int off = 16; off > 0; off >>= 1) vvl += __shfl_xor(vvl, off);
        if (b == 0) vvs = vvl;
    }
    __syncthreads();

    if (w == 0) {
        float acc = bias[o] + (partial[0][b] + partial[1][b])
                            + (partial[2][b] + partial[3][b]);
        acc = acc > 0.f ? acc : 0.01f * acc;          // h2[o][b]
        const float contrib = vvs * acc;              // vv[o] * h2[o][b]
        atomicAdd(&outacc[(o & (NSLOTS - 1)) * BB + b], contrib);
        __threadfence();                               // make adds visible
        int old = 0;
        if (b == 0) old = (int)atomicAdd((unsigned int*)ticket, 1u);
        old = __shfl(old, 0);
        if (old == DD - 1) {                           // last block finishes
            __threadfence();
            float s = cval[0];
            #pragma unroll
            for (int slot = 0; slot < NSLOTS; ++slot)
                s += atomicAdd(&outacc[slot * BB + b], 0.0f);  // coherent read
            out[b] = 1.f / (1.f + __expf(-s));
        }
    }
}

// ---------------------------------------------------------------------------
extern "C" void kernel_launch(void* const* d_in, const int* in_sizes, int n_in,
                              void* d_out, int out_size, void* d_ws, size_t ws_size,
                              hipStream_t stream)
{
    const float* pitches    = (const float*)d_in[0];
    const float* velocities = (const float*)d_in[1];
    const float* durations  = (const float*)d_in[2];
    const float* steps      = (const float*)d_in[3];
    const float* Wp  = (const float*)d_in[4];
    const float* bp  = (const float*)d_in[5];
    const float* Wv  = (const float*)d_in[6];
    const float* bv  = (const float*)d_in[7];
    const float* Wd  = (const float*)d_in[8];
    const float* bd  = (const float*)d_in[9];
    const float* Wst = (const float*)d_in[10];
    const float* bs  = (const float*)d_in[11];
    const float* W1  = (const float*)d_in[12];
    const float* b1  = (const float*)d_in[13];
    const float* W2  = (const float*)d_in[14];
    const float* b2  = (const float*)d_in[15];
    const float* Wi  = (const float*)d_in[16];
    const float* bi  = (const float*)d_in[17];
    const float* W3  = (const float*)d_in[18];
    const float* b3  = (const float*)d_in[19];

    float* ws     = (float*)d_ws;
    float* addT   = ws;            // 500*64
    float* h1T    = ws + 32000;    // 500*64
    float* vpart  = ws + 64000;    // 32*512
    float* outacc = ws + 80384;    // 16*64
    float* ticket = ws + 81408;    // 1 (as unsigned)
    float* cval   = ws + 81409;    // 1

    float* out = (float*)d_out;    // [64,1] fp32

    k_front<<<157, 256, 0, stream>>>(pitches, velocities, durations, steps,
                                     Wp, bp, Wv, bv, Wd, bd, Wst, bs,
                                     Wi, W3, bi, b3,
                                     addT, vpart, outacc, ticket, cval);
    k_dense1<<<DD, 256, 0, stream>>>(addT, W1, b1, h1T);
    k_dense2_out<<<DD, 256, 0, stream>>>(h1T, W2, b2, vpart, cval,
                                         outacc, ticket, out);
}